// Round 1
// baseline (888.279 us; speedup 1.0000x reference)
//
#include <hip/hip_runtime.h>
#include <hip/hip_bf16.h>

#define NN 3072
#define FIN 512
#define FOUT 256

typedef __attribute__((ext_vector_type(8))) short short8;
typedef __attribute__((ext_vector_type(4))) float f32x4;

__device__ __forceinline__ short f2bf(float f) {
  union { float f; unsigned u; } v; v.f = f;
  unsigned r = v.u + 0x7fffu + ((v.u >> 16) & 1u);  // RNE
  return (short)(r >> 16);
}

// ---------------- prep kernels ----------------

// adj -> bf16 copy + dinv[m] = 1/(rowsum(hL)+i) = (r/(r^2+1), -1/(r^2+1)), r = h*(1-rowsum(adj))
__global__ __launch_bounds__(256) void prep_adj(const float* __restrict__ adj,
    short* __restrict__ adjbf, float2* __restrict__ dinv, const float* __restrict__ hptr)
{
  int m = blockIdx.x;
  int tid = threadIdx.x;
  const float4* row = (const float4*)(adj + (size_t)m * NN);
  short4* obf = (short4*)(adjbf + (size_t)m * NN);
  float sum = 0.f;
#pragma unroll
  for (int i = 0; i < NN / 4 / 256; ++i) {
    int idx = i * 256 + tid;
    float4 v = row[idx];
    sum += (v.x + v.y) + (v.z + v.w);
    obf[idx] = make_short4(f2bf(v.x), f2bf(v.y), f2bf(v.z), f2bf(v.w));
  }
#pragma unroll
  for (int off = 32; off > 0; off >>= 1) sum += __shfl_down(sum, off, 64);
  __shared__ float red[4];
  if ((tid & 63) == 0) red[tid >> 6] = sum;
  __syncthreads();
  if (tid == 0) {
    float s = red[0] + red[1] + red[2] + red[3];
    float h = hptr[0];
    float r = h * (1.f - s);
    float den = r * r + 1.f;
    dinv[m] = make_float2(r / den, -1.f / den);
  }
}

__global__ __launch_bounds__(256) void prep_x(const float* __restrict__ x, short* __restrict__ xbf) {
  int idx = blockIdx.x * 256 + threadIdx.x;   // over (3072*512)/4 float4s
  float4 v = ((const float4*)x)[idx];
  ((short4*)xbf)[idx] = make_short4(f2bf(v.x), f2bf(v.y), f2bf(v.z), f2bf(v.w));
}

// wpack [1280][512] bf16, transposed weights, r/i interleaved rows:
// rows 0-511: P1 (wr[1]/wi[1]); rows 512-1023: P0 (wr[0]/wi[0]); rows 1024-1279: w0
__global__ __launch_bounds__(256) void prep_w(const float* __restrict__ w0,
    const float* __restrict__ wr, const float* __restrict__ wi, short* __restrict__ wpack)
{
  int idx = blockIdx.x * 256 + threadIdx.x;   // [1280][512]
  int f = idx & 511;
  int i = idx >> 9;
  float v;
  if (i < 1024) {
    int j = (i < 512) ? 1 : 0;
    int local = i & 511;
    int c = local >> 1;
    const float* src = (local & 1) ? wi : wr;
    v = src[((size_t)j * FIN + f) * FOUT + c];
  } else {
    v = w0[(size_t)f * FOUT + (i - 1024)];
  }
  wpack[idx] = f2bf(v);
}

// ---------------- fused GEMM + epilogue ----------------
// D[i][j] = sum_k Apan[i][k] * Badj[j][k]   (i: panel rows, j: nodes, K contiguous both)
// mode 0: write D (f32 always; bf16 for i<1024)
// mode 1 (A-op): out = hL@V - iV  -> out_r = h*(Vr - Cr) + Vi ; out_i = h*(Vi - Ci) - Vr
// mode 2 (G-it): t = hL@y + iy ;  e = V - t ; y' = y + dinv*e (complex)
__global__ __launch_bounds__(256) void gemm_step(
    const short* __restrict__ Apan, int lda,
    const short* __restrict__ Badj, int ldb,
    int K, int mode,
    const float* __restrict__ Vin,
    const float* __restrict__ Yin,
    float* __restrict__ Fout,
    short* __restrict__ Bout,
    const float2* __restrict__ dinv,
    const float* __restrict__ hptr)
{
  int tid = threadIdx.x;
  int lane = tid & 63;
  int wid = tid >> 6;
  int wr_ = wid >> 1, wc = wid & 1;
  int i0 = blockIdx.y * 128 + wr_ * 64;
  int j0 = blockIdx.x * 128 + wc * 64;

  int l15 = lane & 15;
  int kg = (lane >> 4) << 3;   // k offset of this lane group: 0,8,16,24

  const short* aptr = Apan + (size_t)(i0 + l15) * lda + kg;
  const short* bptr = Badj + (size_t)(j0 + l15) * ldb + kg;

  f32x4 acc[4][4];
#pragma unroll
  for (int a = 0; a < 4; a++)
#pragma unroll
    for (int b = 0; b < 4; b++) acc[a][b] = (f32x4){0.f, 0.f, 0.f, 0.f};

#pragma unroll 2
  for (int k = 0; k < K; k += 32) {
    short8 af[4], bfg[4];
#pragma unroll
    for (int a = 0; a < 4; a++)
      af[a] = *(const short8*)(aptr + (size_t)a * 16 * lda + k);
#pragma unroll
    for (int b = 0; b < 4; b++)
      bfg[b] = *(const short8*)(bptr + (size_t)b * 16 * ldb + k);
#pragma unroll
    for (int a = 0; a < 4; a++)
#pragma unroll
      for (int b = 0; b < 4; b++)
        acc[a][b] = __builtin_amdgcn_mfma_f32_16x16x32_bf16(af[a], bfg[b], acc[a][b], 0, 0, 0);
  }

  float hv = hptr[0];
  int ibase = i0 + ((lane >> 4) << 2);   // + a*16 + q  (q pairs: even=real, odd=imag)
#pragma unroll
  for (int a = 0; a < 4; a++) {
    int ia = ibase + a * 16;
#pragma unroll
    for (int b = 0; b < 4; b++) {
      int jb = j0 + b * 16 + l15;
      f32x4 c = acc[a][b];
      if (mode == 0) {
#pragma unroll
        for (int q = 0; q < 4; q++) {
          size_t off = (size_t)(ia + q) * NN + jb;
          Fout[off] = c[q];
          if (ia + q < 1024) Bout[off] = f2bf(c[q]);
        }
      } else if (mode == 1) {
#pragma unroll
        for (int p = 0; p < 4; p += 2) {
          size_t offr = (size_t)(ia + p) * NN + jb;
          size_t offi = offr + NN;
          float vr = Vin[offr], vi = Vin[offi];
          float outr = hv * (vr - c[p])     + vi;
          float outi = hv * (vi - c[p + 1]) - vr;
          Fout[offr] = outr; Fout[offi] = outi;
          Bout[offr] = f2bf(outr); Bout[offi] = f2bf(outi);
        }
      } else {
        float2 dv = dinv[jb];
#pragma unroll
        for (int p = 0; p < 4; p += 2) {
          size_t offr = (size_t)(ia + p) * NN + jb;
          size_t offi = offr + NN;
          float vr = Vin[offr], vi = Vin[offi];
          float yr = Yin[offr], yi = Yin[offi];
          float tr_ = hv * (yr - c[p])     - yi;
          float ti_ = hv * (yi - c[p + 1]) + yr;
          float er = vr - tr_, ei = vi - ti_;
          float nyr = yr + dv.x * er - dv.y * ei;
          float nyi = yi + dv.x * ei + dv.y * er;
          Fout[offr] = nyr; Fout[offi] = nyi;
          Bout[offr] = f2bf(nyr); Bout[offi] = f2bf(nyi);
        }
      }
    }
  }
}

// ---------------- final: out[node][c] = relu(out0T[c][node] + 2*(U_r + S_r)) ----------------
__global__ __launch_bounds__(256) void final_out(
    const float* __restrict__ Vbuf,   // rows 1024..1279 = out0T
    const float* __restrict__ ybuf,   // chain1 rows 0..511 (interleaved), chain2 rows 512..1023
    float* __restrict__ out)
{
  __shared__ float t[64][65];
  int n0 = blockIdx.x * 64;
  int c0 = blockIdx.y * 64;
  int lane = threadIdx.x & 63;
  int wv = threadIdx.x >> 6;
#pragma unroll
  for (int s = 0; s < 16; s++) {
    int c = c0 + wv + s * 4;
    float o0 = Vbuf[(size_t)(1024 + c) * NN + n0 + lane];
    float u  = ybuf[(size_t)(2 * c) * NN + n0 + lane];
    float sv = ybuf[(size_t)(512 + 2 * c) * NN + n0 + lane];
    float v = o0 + 2.f * (u + sv);
    t[lane][wv + s * 4] = v > 0.f ? v : 0.f;
  }
  __syncthreads();
#pragma unroll
  for (int s = 0; s < 16; s++) {
    int nl = wv + s * 4;
    out[(size_t)(n0 + nl) * FOUT + c0 + lane] = t[nl][lane];
  }
}

extern "C" void kernel_launch(void* const* d_in, const int* in_sizes, int n_in,
                              void* d_out, int out_size, void* d_ws, size_t ws_size,
                              hipStream_t stream) {
  const float* x   = (const float*)d_in[0];
  const float* adj = (const float*)d_in[1];
  const float* h   = (const float*)d_in[2];
  const float* w0  = (const float*)d_in[3];
  const float* wr  = (const float*)d_in[4];
  const float* wi  = (const float*)d_in[5];
  float* out = (float*)d_out;

  char* ws = (char*)d_ws;
  size_t off = 0;
  auto alloc = [&](size_t bytes) {
    char* p = ws + off;
    off += (bytes + 255) & ~(size_t)255;
    return p;
  };
  short*  adjbf = (short*)alloc((size_t)NN * NN * 2);
  short*  xbf   = (short*)alloc((size_t)NN * FIN * 2);
  short*  wpack = (short*)alloc((size_t)1280 * FIN * 2);
  float2* dinv  = (float2*)alloc((size_t)NN * sizeof(float2));
  float*  Vbuf  = (float*)alloc((size_t)1280 * NN * 4);
  float*  ybuf  = (float*)alloc((size_t)1024 * NN * 4);
  short*  b0    = (short*)alloc((size_t)1024 * NN * 2);
  short*  b1    = (short*)alloc((size_t)1024 * NN * 2);

  prep_adj<<<NN, 256, 0, stream>>>(adj, adjbf, dinv, h);
  prep_x<<<(NN * FIN / 4) / 256, 256, 0, stream>>>(x, xbf);
  prep_w<<<(1280 * FIN) / 256, 256, 0, stream>>>(w0, wr, wi, wpack);

  // GEMM0: [1280][3072] = wpack(x)  K=512 -> Vbuf (P1|P0|out0T), b0 (bf16 panels)
  gemm_step<<<dim3(24, 10), 256, 0, stream>>>(wpack, FIN, xbf, FIN, FIN, 0,
      nullptr, nullptr, Vbuf, b0, dinv, h);
  // wide A (rows 0-1023): V' = A(P), in-place in Vbuf
  gemm_step<<<dim3(24, 8), 256, 0, stream>>>(b0, NN, adjbf, NN, NN, 1,
      Vbuf, nullptr, Vbuf, b1, dinv, h);
  // wide G x3 : rhs = Vbuf, y evolves in ybuf
  gemm_step<<<dim3(24, 8), 256, 0, stream>>>(b1, NN, adjbf, NN, NN, 2,
      Vbuf, Vbuf, ybuf, b0, dinv, h);
  gemm_step<<<dim3(24, 8), 256, 0, stream>>>(b0, NN, adjbf, NN, NN, 2,
      Vbuf, ybuf, ybuf, b1, dinv, h);
  gemm_step<<<dim3(24, 8), 256, 0, stream>>>(b1, NN, adjbf, NN, NN, 2,
      Vbuf, ybuf, ybuf, b0, dinv, h);
  // narrow A (chain1 rows 0-511): V input = ybuf, out -> Vbuf
  gemm_step<<<dim3(24, 4), 256, 0, stream>>>(b0, NN, adjbf, NN, NN, 1,
      ybuf, nullptr, Vbuf, b1, dinv, h);
  // narrow G x3
  gemm_step<<<dim3(24, 4), 256, 0, stream>>>(b1, NN, adjbf, NN, NN, 2,
      Vbuf, Vbuf, ybuf, b0, dinv, h);
  gemm_step<<<dim3(24, 4), 256, 0, stream>>>(b0, NN, adjbf, NN, NN, 2,
      Vbuf, ybuf, ybuf, b1, dinv, h);
  gemm_step<<<dim3(24, 4), 256, 0, stream>>>(b1, NN, adjbf, NN, NN, 2,
      Vbuf, ybuf, ybuf, b0, dinv, h);

  final_out<<<dim3(48, 4), 256, 0, stream>>>(Vbuf, ybuf, out);
}

// Round 2
// 387.605 us; speedup vs baseline: 2.2917x; 2.2917x over previous
//
#include <hip/hip_runtime.h>
#include <hip/hip_bf16.h>

#define NN 3072
#define FIN 512
#define FOUT 256

typedef __attribute__((ext_vector_type(8))) short short8;
typedef __attribute__((ext_vector_type(4))) float f32x4;

__device__ __forceinline__ short f2bf(float f) {
  union { float f; unsigned u; } v; v.f = f;
  unsigned r = v.u + 0x7fffu + ((v.u >> 16) & 1u);  // RNE
  return (short)(r >> 16);
}

__device__ __forceinline__ void glds16(const short* g, short* l) {
  __builtin_amdgcn_global_load_lds(
      (const __attribute__((address_space(1))) unsigned*)g,
      (__attribute__((address_space(3))) unsigned*)l, 16, 0, 0);
}

template<int N> __device__ __forceinline__ void wait_vm() {
  if constexpr (N == 0)      asm volatile("s_waitcnt vmcnt(0)" ::: "memory");
  else if constexpr (N == 6) asm volatile("s_waitcnt vmcnt(6)" ::: "memory");
  else                       asm volatile("s_waitcnt vmcnt(8)" ::: "memory");
}

// ---------------- prep kernels (unchanged from passing round 1) ----------------

__global__ __launch_bounds__(256) void prep_adj(const float* __restrict__ adj,
    short* __restrict__ adjbf, float2* __restrict__ dinv, const float* __restrict__ hptr)
{
  int m = blockIdx.x;
  int tid = threadIdx.x;
  const float4* row = (const float4*)(adj + (size_t)m * NN);
  short4* obf = (short4*)(adjbf + (size_t)m * NN);
  float sum = 0.f;
#pragma unroll
  for (int i = 0; i < NN / 4 / 256; ++i) {
    int idx = i * 256 + tid;
    float4 v = row[idx];
    sum += (v.x + v.y) + (v.z + v.w);
    obf[idx] = make_short4(f2bf(v.x), f2bf(v.y), f2bf(v.z), f2bf(v.w));
  }
#pragma unroll
  for (int off = 32; off > 0; off >>= 1) sum += __shfl_down(sum, off, 64);
  __shared__ float red[4];
  if ((tid & 63) == 0) red[tid >> 6] = sum;
  __syncthreads();
  if (tid == 0) {
    float s = red[0] + red[1] + red[2] + red[3];
    float h = hptr[0];
    float r = h * (1.f - s);
    float den = r * r + 1.f;
    dinv[m] = make_float2(r / den, -1.f / den);
  }
}

__global__ __launch_bounds__(256) void prep_x(const float* __restrict__ x, short* __restrict__ xbf) {
  int idx = blockIdx.x * 256 + threadIdx.x;
  float4 v = ((const float4*)x)[idx];
  ((short4*)xbf)[idx] = make_short4(f2bf(v.x), f2bf(v.y), f2bf(v.z), f2bf(v.w));
}

__global__ __launch_bounds__(256) void prep_w(const float* __restrict__ w0,
    const float* __restrict__ wr, const float* __restrict__ wi, short* __restrict__ wpack)
{
  int idx = blockIdx.x * 256 + threadIdx.x;   // [1280][512]
  int f = idx & 511;
  int i = idx >> 9;
  float v;
  if (i < 1024) {
    int j = (i < 512) ? 1 : 0;
    int local = i & 511;
    int c = local >> 1;
    const float* src = (local & 1) ? wi : wr;
    v = src[((size_t)j * FIN + f) * FOUT + c];
  } else {
    v = w0[(size_t)f * FOUT + (i - 1024)];
  }
  wpack[idx] = f2bf(v);
}

// ---------------- pipelined GEMM + fused epilogue ----------------
// Block: 512 threads = 8 waves = 4 spatial (2x2) x 2 K-split groups.
// Tile: BM x 128, BK=64, LDS double-buffered per group, glds16 staging with
// XOR-chunk swizzle (source-side) matched on ds_read side. Counted vmcnt.
template<int BM, int MR, int MODE, int KTOT>
__global__ __launch_bounds__(512, 2) void gemm_k(
    const short* __restrict__ Apan, int lda,
    const short* __restrict__ Badj, int ldb,
    const float* __restrict__ Vin,
    const float* __restrict__ Yin,
    float* __restrict__ Fout,
    short* __restrict__ Bout,
    const float2* __restrict__ dinv,
    const float* __restrict__ hptr)
{
  constexpr int BK = 64;
  constexpr int NT = KTOT / (2 * BK);      // steps per K-group
  constexpr int ALOADS = BM / 8;           // wave-loads to fill A tile (8 rows each)
  constexpr int BLOADS = 16;               // 128 rows / 8
  constexpr int LPW = (ALOADS + BLOADS) / 4;  // glds per wave per stage (8 or 6)

  __shared__ short As[2][2][BM * BK];      // [group][buf][row*64]
  __shared__ short Bs[2][2][128 * BK];

  const int tid  = threadIdx.x;
  const int lane = tid & 63;
  const int w    = tid >> 6;
  const int g    = w >> 2;                 // K-split group
  const int wg   = w & 3;                  // spatial wave
  const int wrow = wg >> 1, wcol = wg & 1;
  const int l15  = lane & 15;

  const int i0 = blockIdx.y * BM;
  const int j0 = blockIdx.x * 128;
  const int kbase = g * (KTOT / 2);

  // staging lane geometry: wave covers 8 rows x 8 chunks(16B); source chunk XOR-swizzled
  const int srow = lane >> 3;
  const int scol = ((lane & 7) ^ srow) * 8;   // element offset within row

  const short* aSrc = Apan + (size_t)i0 * lda + kbase;
  const short* bSrc = Badj + (size_t)j0 * ldb + kbase;

  auto STAGE = [&](int t) {
    const int k0 = t * BK;
    short* at = As[g][t & 1];
    short* bt = Bs[g][t & 1];
#pragma unroll
    for (int li = 0; li < ALOADS / 4; ++li) {
      int rb = (wg + li * 4) * 8;
      glds16(aSrc + (size_t)(rb + srow) * lda + k0 + scol, at + rb * BK);
    }
#pragma unroll
    for (int li = 0; li < BLOADS / 4; ++li) {
      int rb = (wg + li * 4) * 8;
      glds16(bSrc + (size_t)(rb + srow) * ldb + k0 + scol, bt + rb * BK);
    }
  };

  f32x4 acc[MR][4];
#pragma unroll
  for (int a = 0; a < MR; a++)
#pragma unroll
    for (int b = 0; b < 4; b++) acc[a][b] = (f32x4){0.f, 0.f, 0.f, 0.f};

  STAGE(0);
  STAGE(1);

  for (int t = 0; t < NT; ++t) {
    if (t < NT - 1) wait_vm<LPW>(); else wait_vm<0>();
    __builtin_amdgcn_s_barrier();
    asm volatile("" ::: "memory");

    const short* at = As[g][t & 1];
    const short* bt = Bs[g][t & 1];
#pragma unroll
    for (int kk = 0; kk < 2; ++kk) {
      const int cbase = kk * 4 + (lane >> 4);
      short8 af[MR], bfg[4];
#pragma unroll
      for (int a = 0; a < MR; ++a) {
        int ra = wrow * (MR * 16) + a * 16 + l15;
        int c = cbase ^ (ra & 7);
        af[a] = *(const short8*)(at + ra * BK + c * 8);
      }
#pragma unroll
      for (int b = 0; b < 4; ++b) {
        int rb = wcol * 64 + b * 16 + l15;
        int c = cbase ^ (rb & 7);
        bfg[b] = *(const short8*)(bt + rb * BK + c * 8);
      }
      __builtin_amdgcn_s_setprio(1);
#pragma unroll
      for (int a = 0; a < MR; ++a)
#pragma unroll
        for (int b = 0; b < 4; ++b)
          acc[a][b] = __builtin_amdgcn_mfma_f32_16x16x32_bf16(af[a], bfg[b], acc[a][b], 0, 0, 0);
      __builtin_amdgcn_s_setprio(0);
    }

    asm volatile("" ::: "memory");
    __builtin_amdgcn_s_barrier();
    asm volatile("" ::: "memory");
    if (t + 2 < NT) STAGE(t + 2);
  }

  // ---- split-K reduction (reuse As as [BM][128] f32 scratch; sizes match exactly) ----
  float* red = (float*)&As[0][0][0];
  const int rl0 = wrow * (MR * 16) + ((lane >> 4) << 2);
  const int cl0 = wcol * 64 + l15;
  if (g == 1) {
#pragma unroll
    for (int a = 0; a < MR; ++a)
#pragma unroll
      for (int b = 0; b < 4; ++b)
#pragma unroll
        for (int q = 0; q < 4; ++q)
          red[(size_t)(rl0 + a * 16 + q) * 128 + cl0 + b * 16] = acc[a][b][q];
  }
  __syncthreads();

  if (g == 0) {
    const float hv = hptr[0];
#pragma unroll
    for (int a = 0; a < MR; ++a) {
#pragma unroll
      for (int b = 0; b < 4; ++b) {
        f32x4 c = acc[a][b];
        const int rl = rl0 + a * 16;
        const int cl = cl0 + b * 16;
#pragma unroll
        for (int q = 0; q < 4; ++q)
          c[q] += red[(size_t)(rl + q) * 128 + cl];
        const int ia = i0 + rl;
        const int jb = j0 + cl;
        if (MODE == 0) {
#pragma unroll
          for (int q = 0; q < 4; ++q) {
            size_t off = (size_t)(ia + q) * NN + jb;
            Fout[off] = c[q];
            if (ia + q < 1024) Bout[off] = f2bf(c[q]);
          }
        } else if (MODE == 1) {
#pragma unroll
          for (int p = 0; p < 4; p += 2) {
            size_t offr = (size_t)(ia + p) * NN + jb;
            size_t offi = offr + NN;
            float vr = Vin[offr], vi = Vin[offi];
            float outr = hv * (vr - c[p])     + vi;
            float outi = hv * (vi - c[p + 1]) - vr;
            Fout[offr] = outr; Fout[offi] = outi;
            Bout[offr] = f2bf(outr); Bout[offi] = f2bf(outi);
          }
        } else {
#pragma unroll
          for (int p = 0; p < 4; p += 2) {
            size_t offr = (size_t)(ia + p) * NN + jb;
            size_t offi = offr + NN;
            float2 dv = dinv[jb];
            float vr = Vin[offr], vi = Vin[offi];
            float yr = Yin[offr], yi = Yin[offi];
            float tr_ = hv * (yr - c[p])     - yi;
            float ti_ = hv * (yi - c[p + 1]) + yr;
            float er = vr - tr_, ei = vi - ti_;
            float nyr = yr + dv.x * er - dv.y * ei;
            float nyi = yi + dv.x * ei + dv.y * er;
            Fout[offr] = nyr; Fout[offi] = nyi;
            Bout[offr] = f2bf(nyr); Bout[offi] = f2bf(nyi);
          }
        }
      }
    }
  }
}

// ---------------- final: out[node][c] = relu(out0T[c][node] + 2*(term1 + term2)) ----------------
__global__ __launch_bounds__(256) void final_out(
    const float* __restrict__ Vbuf,
    const float* __restrict__ ybuf,
    float* __restrict__ out)
{
  __shared__ float t[64][65];
  int n0 = blockIdx.x * 64;
  int c0 = blockIdx.y * 64;
  int lane = threadIdx.x & 63;
  int wv = threadIdx.x >> 6;
#pragma unroll
  for (int s = 0; s < 16; s++) {
    int c = c0 + wv + s * 4;
    float o0 = Vbuf[(size_t)(1024 + c) * NN + n0 + lane];
    float u  = ybuf[(size_t)(2 * c) * NN + n0 + lane];
    float sv = ybuf[(size_t)(512 + 2 * c) * NN + n0 + lane];
    float v = o0 + 2.f * (u + sv);
    t[lane][wv + s * 4] = v > 0.f ? v : 0.f;
  }
  __syncthreads();
#pragma unroll
  for (int s = 0; s < 16; s++) {
    int nl = wv + s * 4;
    out[(size_t)(n0 + nl) * FOUT + c0 + lane] = t[nl][lane];
  }
}

extern "C" void kernel_launch(void* const* d_in, const int* in_sizes, int n_in,
                              void* d_out, int out_size, void* d_ws, size_t ws_size,
                              hipStream_t stream) {
  const float* x   = (const float*)d_in[0];
  const float* adj = (const float*)d_in[1];
  const float* h   = (const float*)d_in[2];
  const float* w0  = (const float*)d_in[3];
  const float* wr  = (const float*)d_in[4];
  const float* wi  = (const float*)d_in[5];
  float* out = (float*)d_out;

  char* ws = (char*)d_ws;
  size_t off = 0;
  auto alloc = [&](size_t bytes) {
    char* p = ws + off;
    off += (bytes + 255) & ~(size_t)255;
    return p;
  };
  short*  adjbf = (short*)alloc((size_t)NN * NN * 2);
  short*  xbf   = (short*)alloc((size_t)NN * FIN * 2);
  short*  wpack = (short*)alloc((size_t)1280 * FIN * 2);
  float2* dinv  = (float2*)alloc((size_t)NN * sizeof(float2));
  float*  Vbuf  = (float*)alloc((size_t)1280 * NN * 4);
  float*  ybuf  = (float*)alloc((size_t)1024 * NN * 4);
  short*  b0    = (short*)alloc((size_t)1024 * NN * 2);
  short*  b1    = (short*)alloc((size_t)1024 * NN * 2);

  prep_adj<<<NN, 256, 0, stream>>>(adj, adjbf, dinv, h);
  prep_x<<<(NN * FIN / 4) / 256, 256, 0, stream>>>(x, xbf);
  prep_w<<<(1280 * FIN) / 256, 256, 0, stream>>>(w0, wr, wi, wpack);

  // GEMM0: [1280][3072] = wpack @ xbf^T (K=512) -> Vbuf (P1|P0|out0T), b0 bf16 panels
  gemm_k<128, 4, 0, FIN><<<dim3(24, 10), 512, 0, stream>>>(
      wpack, FIN, xbf, FIN, nullptr, nullptr, Vbuf, b0, dinv, h);
  // wide A (rows 0-1023): V' = A(P), in-place in Vbuf
  gemm_k<128, 4, 1, NN><<<dim3(24, 8), 512, 0, stream>>>(
      b0, NN, adjbf, NN, Vbuf, nullptr, Vbuf, b1, dinv, h);
  // wide G x3
  gemm_k<128, 4, 2, NN><<<dim3(24, 8), 512, 0, stream>>>(
      b1, NN, adjbf, NN, Vbuf, Vbuf, ybuf, b0, dinv, h);
  gemm_k<128, 4, 2, NN><<<dim3(24, 8), 512, 0, stream>>>(
      b0, NN, adjbf, NN, Vbuf, ybuf, ybuf, b1, dinv, h);
  gemm_k<128, 4, 2, NN><<<dim3(24, 8), 512, 0, stream>>>(
      b1, NN, adjbf, NN, Vbuf, ybuf, ybuf, b0, dinv, h);
  // narrow A (chain rows 0-511): input = ybuf rows 0-511, out -> Vbuf rows 0-511
  gemm_k<64, 2, 1, NN><<<dim3(24, 8), 512, 0, stream>>>(
      b0, NN, adjbf, NN, ybuf, nullptr, Vbuf, b1, dinv, h);
  // narrow G x3
  gemm_k<64, 2, 2, NN><<<dim3(24, 8), 512, 0, stream>>>(
      b1, NN, adjbf, NN, Vbuf, Vbuf, ybuf, b0, dinv, h);
  gemm_k<64, 2, 2, NN><<<dim3(24, 8), 512, 0, stream>>>(
      b0, NN, adjbf, NN, Vbuf, ybuf, ybuf, b1, dinv, h);
  gemm_k<64, 2, 2, NN><<<dim3(24, 8), 512, 0, stream>>>(
      b1, NN, adjbf, NN, Vbuf, ybuf, ybuf, b0, dinv, h);

  final_out<<<dim3(48, 4), 256, 0, stream>>>(Vbuf, ybuf, out);
}